// Round 10
// baseline (140.602 us; speedup 1.0000x reference)
//
#include <hip/hip_runtime.h>

#define HDIM 8
#define CHUNK 16   // steps per LDS chunk (T=512 -> 32 chunks)

typedef float v4f __attribute__((ext_vector_type(4)));
typedef float v2f __attribute__((ext_vector_type(2)));

// ---- fast device math (v_exp_f32 / v_rcp_f32) ----
__device__ __forceinline__ float ex2(float x) {
#if __has_builtin(__builtin_amdgcn_exp2f)
    return __builtin_amdgcn_exp2f(x);
#else
    return exp2f(x);
#endif
}
__device__ __forceinline__ float rcp(float x) {
#if __has_builtin(__builtin_amdgcn_rcpf)
    return __builtin_amdgcn_rcpf(x);
#else
    return 1.0f / x;
#endif
}

// v_mov_b32_dpp row_ror:N (N immediate). 0x120+N = ROW_ROR DPP ctrl.
#define DPP_ROR(v, N)                                                        \
    __int_as_float(__builtin_amdgcn_update_dpp(                              \
        0, __float_as_int(v), 0x120 + (N), 0xF, 0xF, true))

// Keep-alive pin for 16 named vector values.
#define KEEPALIVE16(a)                                                       \
    asm volatile("" : "+v"(a##0), "+v"(a##1), "+v"(a##2), "+v"(a##3),        \
                      "+v"(a##4), "+v"(a##5), "+v"(a##6), "+v"(a##7),        \
                      "+v"(a##8), "+v"(a##9), "+v"(a##10), "+v"(a##11),      \
                      "+v"(a##12), "+v"(a##13), "+v"(a##14), "+v"(a##15))

// One GRU step: 3 init FMAs + 21 fused v_fmac_f32_dpp + gates.
// Requires in scope: float hj, wr[8], wz[8], wn[8], bhn.
#define FMAC3(ROT, M)                                                        \
    "v_fmac_f32_dpp %[ar], %[h], %[wr" #M "] row_ror:" #ROT                  \
    " row_mask:0xf bank_mask:0xf\n\t"                                        \
    "v_fmac_f32_dpp %[az], %[h], %[wz" #M "] row_ror:" #ROT                  \
    " row_mask:0xf bank_mask:0xf\n\t"                                        \
    "v_fmac_f32_dpp %[an], %[h], %[wn" #M "] row_ror:" #ROT                  \
    " row_mask:0xf bank_mask:0xf\n\t"

#define STEP(P)                                                              \
    {                                                                        \
        float ar = fmaf(wr[0], hj, (P).x);                                   \
        float az = fmaf(wz[0], hj, (P).y);                                   \
        float an_ = fmaf(wn[0], hj, bhn);                                    \
        asm volatile(                                                        \
            FMAC3(2, 1) FMAC3(4, 2) FMAC3(6, 3) FMAC3(8, 4)                  \
            FMAC3(10, 5) FMAC3(12, 6) FMAC3(14, 7)                           \
            : [ar] "+v"(ar), [az] "+v"(az), [an] "+v"(an_)                   \
            : [h] "v"(hj),                                                   \
              [wr1] "v"(wr[1]), [wz1] "v"(wz[1]), [wn1] "v"(wn[1]),          \
              [wr2] "v"(wr[2]), [wz2] "v"(wz[2]), [wn2] "v"(wn[2]),          \
              [wr3] "v"(wr[3]), [wz3] "v"(wz[3]), [wn3] "v"(wn[3]),          \
              [wr4] "v"(wr[4]), [wz4] "v"(wz[4]), [wn4] "v"(wn[4]),          \
              [wr5] "v"(wr[5]), [wz5] "v"(wz[5]), [wn5] "v"(wn[5]),          \
              [wr6] "v"(wr[6]), [wz6] "v"(wz[6]), [wn6] "v"(wn[6]),          \
              [wr7] "v"(wr[7]), [wz7] "v"(wz[7]), [wn7] "v"(wn[7]));         \
        float r = rcp(1.0f + ex2(ar));                                       \
        float z = rcp(1.0f + ex2(az));                                       \
        float u = fmaf(r, an_, (P).z);                                       \
        float n = fmaf(-2.0f, rcp(1.0f + ex2(u)), 1.0f);                     \
        hj = fmaf(z, hj - n, n);                                             \
    }

// ---- producer: prescaled input projections for one 16-step chunk ----
template <int IN, int STRIDE>
__device__ __forceinline__ void produce_chunk(
    const float* __restrict__ xb, int t0,
    const float (&ur)[4], const float (&uz)[4], const float (&un)[4],
    float cr, float cz, float cn,
    float4* __restrict__ dst, int lane)
{
    const float* bp = xb + (size_t)t0 * STRIDE;
#define PLOAD4(i) v4f x##i = *reinterpret_cast<const v4f*>(bp + (i) * STRIDE);
#define PLOAD2(i) v2f x##i = *reinterpret_cast<const v2f*>(bp + (i) * STRIDE);
#define PSTORE(i)                                                            \
    {                                                                        \
        float a = cr, b = cz, c = cn;                                        \
        _Pragma("unroll")                                                    \
        for (int i2 = 0; i2 < IN; ++i2) {                                    \
            a = fmaf(ur[i2], x##i[i2], a);                                   \
            b = fmaf(uz[i2], x##i[i2], b);                                   \
            c = fmaf(un[i2], x##i[i2], c);                                   \
        }                                                                    \
        dst[(i) * 64 + lane] = make_float4(a, b, c, 0.0f);                   \
    }
    if constexpr (IN == 4) {
        PLOAD4(0) PLOAD4(1) PLOAD4(2) PLOAD4(3) PLOAD4(4) PLOAD4(5)
        PLOAD4(6) PLOAD4(7) PLOAD4(8) PLOAD4(9) PLOAD4(10) PLOAD4(11)
        PLOAD4(12) PLOAD4(13) PLOAD4(14) PLOAD4(15)
        KEEPALIVE16(x);
        PSTORE(0) PSTORE(1) PSTORE(2) PSTORE(3) PSTORE(4) PSTORE(5)
        PSTORE(6) PSTORE(7) PSTORE(8) PSTORE(9) PSTORE(10) PSTORE(11)
        PSTORE(12) PSTORE(13) PSTORE(14) PSTORE(15)
    } else {
        PLOAD2(0) PLOAD2(1) PLOAD2(2) PLOAD2(3) PLOAD2(4) PLOAD2(5)
        PLOAD2(6) PLOAD2(7) PLOAD2(8) PLOAD2(9) PLOAD2(10) PLOAD2(11)
        PLOAD2(12) PLOAD2(13) PLOAD2(14) PLOAD2(15)
        KEEPALIVE16(x);
        PSTORE(0) PSTORE(1) PSTORE(2) PSTORE(3) PSTORE(4) PSTORE(5)
        PSTORE(6) PSTORE(7) PSTORE(8) PSTORE(9) PSTORE(10) PSTORE(11)
        PSTORE(12) PSTORE(13) PSTORE(14) PSTORE(15)
    }
#undef PLOAD4
#undef PLOAD2
#undef PSTORE
}

// ---- consumer: 16 recurrence steps; LDS read only in the pinned preload ----
__device__ __forceinline__ float consume_chunk(
    float hj, const float4* __restrict__ src, int lane,
    const float (&wr)[8], const float (&wz)[8], const float (&wn)[8], float bhn)
{
    const v4f* sp = reinterpret_cast<const v4f*>(src);
#define CLOAD(i) v4f p##i = sp[(i) * 64 + lane];
    CLOAD(0) CLOAD(1) CLOAD(2) CLOAD(3) CLOAD(4) CLOAD(5) CLOAD(6) CLOAD(7)
    CLOAD(8) CLOAD(9) CLOAD(10) CLOAD(11) CLOAD(12) CLOAD(13) CLOAD(14) CLOAD(15)
    KEEPALIVE16(p);
#undef CLOAD
    STEP(p0) STEP(p1) STEP(p2) STEP(p3) STEP(p4) STEP(p5) STEP(p6) STEP(p7)
    STEP(p8) STEP(p9) STEP(p10) STEP(p11) STEP(p12) STEP(p13) STEP(p14) STEP(p15)
    return hj;
}

// ---- main kernel (identical to round 9) ----
__global__ __launch_bounds__(256, 1)
void gru_fused_kernel(const float* __restrict__ bbox, const float* __restrict__ flow,
                      const float* __restrict__ Wih_b, const float* __restrict__ Whh_b,
                      const float* __restrict__ bih_b, const float* __restrict__ bhh_b,
                      const float* __restrict__ Wih_f, const float* __restrict__ Whh_f,
                      const float* __restrict__ bih_f, const float* __restrict__ bhh_f,
                      float* __restrict__ out, int T)
{
    const float NL2E = -1.4426950408889634f;  // -log2(e)
    const float L2E2 =  2.8853900817779268f;  //  2*log2(e)

    __shared__ float4 projLDS[2][2][CHUNK * 64];    // 64 KiB, lane-linear slots
    __shared__ float sh[2][8][HDIM];

    const int tid  = threadIdx.x;
    const int wave = tid >> 6;
    const int lane = tid & 63;
    const int gru  = wave & 1;            // 0 = bbox, 1 = flow
    const bool is_cons = (wave < 2);
    const int NC = T / CHUNK;             // 32

    const int eloc = ((lane >> 4) << 1) | (lane & 1);   // element 0..7
    const int j    = (lane & 15) >> 1;                  // hidden unit 0..7

    float wr[8], wz[8], wn[8];
    float bhn = 0.0f;
    float ur[4] = {0, 0, 0, 0}, uz[4] = {0, 0, 0, 0}, un[4] = {0, 0, 0, 0};
    float cr = 0.0f, cz = 0.0f, cn = 0.0f;
    const float* pxb = nullptr;

    if (is_cons) {
        const float* Whh = gru ? Whh_f : Whh_b;
        const float* bhh = gru ? bhh_f : bhh_b;
        float nbp = DPP_ROR((float)j, 2);
        const int dstep = (nbp == (float)((j + 1) & 7)) ? 1 : 7;
#pragma unroll
        for (int m = 0; m < 8; ++m) {
            const int k = (j + dstep * m) & 7;
            wr[m] = NL2E * Whh[(j     ) * HDIM + k];
            wz[m] = NL2E * Whh[(j +  8) * HDIM + k];
            wn[m] = L2E2 * Whh[(j + 16) * HDIM + k];
        }
        bhn = L2E2 * bhh[j + 16];
    } else {
        const float* Wih = gru ? Wih_f : Wih_b;
        const float* bih = gru ? bih_f : bih_b;
        const float* bhh = gru ? bhh_f : bhh_b;
        const int IN = gru ? 2 : 4;
        const int pe = blockIdx.x * 8 + eloc;
        pxb = gru ? (flow + (size_t)pe * T * 50 + 24)
                  : (bbox + (size_t)pe * T * 4);
        for (int i = 0; i < IN; ++i) {
            ur[i] = NL2E * Wih[(j     ) * IN + i];
            uz[i] = NL2E * Wih[(j +  8) * IN + i];
            un[i] = L2E2 * Wih[(j + 16) * IN + i];
        }
        cr = NL2E * (bih[j]     + bhh[j]);
        cz = NL2E * (bih[j + 8] + bhh[j + 8]);
        cn = L2E2 * bih[j + 16];
    }

    float hj = 0.0f;

    if (!is_cons) {
        float4* dst = projLDS[0][gru];
        if (gru == 0) produce_chunk<4, 4 >(pxb, 0, ur, uz, un, cr, cz, cn, dst, lane);
        else          produce_chunk<2, 50>(pxb, 0, ur, uz, un, cr, cz, cn, dst, lane);
    }
    __syncthreads();

    for (int c = 0; c < NC; ++c) {
        if (is_cons) {
            hj = consume_chunk(hj, projLDS[c & 1][gru], lane, wr, wz, wn, bhn);
        } else if (c + 1 < NC) {
            float4* dst = projLDS[(c + 1) & 1][gru];
            if (gru == 0) produce_chunk<4, 4 >(pxb, (c + 1) * CHUNK, ur, uz, un, cr, cz, cn, dst, lane);
            else          produce_chunk<2, 50>(pxb, (c + 1) * CHUNK, ur, uz, un, cr, cz, cn, dst, lane);
        }
        __syncthreads();
    }

    if (is_cons) sh[gru][eloc][j] = hj;
    __syncthreads();
    if (wave == 0) {
        const int e = blockIdx.x * 8 + eloc;
        out[(size_t)e * HDIM + j] = 0.5f * (sh[0][eloc][j] + sh[1][eloc][j]);
    }
}

// ---- DIAGNOSTIC: exact consumer step body, 2*T steps, no LDS/producer/barrier.
// Projections live in 16 pinned registers. Measures chain+issue latency only.
// Output goes to d_ws (guarded); timing read from rocprof / dur_us delta.
__global__ __launch_bounds__(64, 1)
void abl_chain_x2(const float* __restrict__ Whh, const float* __restrict__ bhh,
                  const float* __restrict__ seed, float* __restrict__ ws,
                  size_t ws_bytes, int T)
{
    const float NL2E = -1.4426950408889634f;
    const float L2E2 =  2.8853900817779268f;
    const int lane = threadIdx.x & 63;
    const int j    = (lane & 15) >> 1;

    float nbp = DPP_ROR((float)j, 2);
    const int dstep = (nbp == (float)((j + 1) & 7)) ? 1 : 7;
    float wr[8], wz[8], wn[8];
#pragma unroll
    for (int m = 0; m < 8; ++m) {
        const int k = (j + dstep * m) & 7;
        wr[m] = NL2E * Whh[(j     ) * HDIM + k];
        wz[m] = NL2E * Whh[(j +  8) * HDIM + k];
        wn[m] = L2E2 * Whh[(j + 16) * HDIM + k];
    }
    const float bhn = L2E2 * bhh[j + 16];

    // 16 register-resident projections (values arbitrary but real/bounded)
    const v4f* sp = reinterpret_cast<const v4f*>(seed) + (size_t)blockIdx.x * 64;
#define ALOAD(i) v4f p##i = sp[(i) * 4 + (lane & 3)];
    ALOAD(0) ALOAD(1) ALOAD(2) ALOAD(3) ALOAD(4) ALOAD(5) ALOAD(6) ALOAD(7)
    ALOAD(8) ALOAD(9) ALOAD(10) ALOAD(11) ALOAD(12) ALOAD(13) ALOAD(14) ALOAD(15)
    KEEPALIVE16(p);
#undef ALOAD

    float hj = 0.0f;
    const int NITER = 2 * (T / CHUNK);    // 2*T steps total
    for (int c = 0; c < NITER; ++c) {
        STEP(p0) STEP(p1) STEP(p2) STEP(p3) STEP(p4) STEP(p5) STEP(p6) STEP(p7)
        STEP(p8) STEP(p9) STEP(p10) STEP(p11) STEP(p12) STEP(p13) STEP(p14) STEP(p15)
    }

    const size_t idx = (size_t)blockIdx.x * 64 + lane;
    if ((idx + 1) * sizeof(float) <= ws_bytes) ws[idx] = hj;
}

extern "C" void kernel_launch(void* const* d_in, const int* in_sizes, int n_in,
                              void* d_out, int out_size, void* d_ws, size_t ws_size,
                              hipStream_t stream) {
    const float* bbox  = (const float*)d_in[0];
    const float* flow  = (const float*)d_in[1];
    const float* Wih_b = (const float*)d_in[2];
    const float* Whh_b = (const float*)d_in[3];
    const float* bih_b = (const float*)d_in[4];
    const float* bhh_b = (const float*)d_in[5];
    const float* Wih_f = (const float*)d_in[6];
    const float* Whh_f = (const float*)d_in[7];
    const float* bih_f = (const float*)d_in[8];
    const float* bhh_f = (const float*)d_in[9];
    float* out = (float*)d_out;

    const int B = out_size / HDIM;            // 1024
    const int T = in_sizes[0] / (4 * B);      // 512

    gru_fused_kernel<<<dim3(B / 8), dim3(256), 0, stream>>>(
        bbox, flow, Wih_b, Whh_b, bih_b, bhh_b,
        Wih_f, Whh_f, bih_f, bhh_f, out, T);

    // diagnostic (writes only to d_ws; output unaffected)
    abl_chain_x2<<<dim3(128), dim3(64), 0, stream>>>(
        Whh_b, bhh_b, bbox, (float*)d_ws, ws_size, T);
}

// Round 11
// 93.584 us; speedup vs baseline: 1.5024x; 1.5024x over previous
//
#include <hip/hip_runtime.h>

#define HDIM 8
#define CHUNK 16   // steps per LDS chunk (T=512 -> 32 chunks)

typedef float v4f __attribute__((ext_vector_type(4)));
typedef float v2f __attribute__((ext_vector_type(2)));

// ---- fast device math (v_exp_f32 / v_rcp_f32) ----
__device__ __forceinline__ float ex2(float x) {
#if __has_builtin(__builtin_amdgcn_exp2f)
    return __builtin_amdgcn_exp2f(x);
#else
    return exp2f(x);
#endif
}
__device__ __forceinline__ float rcp(float x) {
#if __has_builtin(__builtin_amdgcn_rcpf)
    return __builtin_amdgcn_rcpf(x);
#else
    return 1.0f / x;
#endif
}

// v_mov_b32_dpp row_ror:N (probe only; hot path uses fused fmac_dpp)
#define DPP_ROR(v, N)                                                        \
    __int_as_float(__builtin_amdgcn_update_dpp(                              \
        0, __float_as_int(v), 0x120 + (N), 0xF, 0xF, true))

// ---- single-instruction asm helpers (order pinned by volatile) ----
#define ASM_FMA(d, a, b, c)                                                  \
    asm volatile("v_fma_f32 %0, %1, %2, %3"                                  \
                 : "=v"(d) : "v"(a), "v"(b), "v"(c))
#define ASM_MULD(d, h, w, ROT)                                               \
    asm volatile("v_mul_f32_dpp %0, %1, %2 row_ror:" #ROT                    \
                 " row_mask:0xf bank_mask:0xf"                               \
                 : "=v"(d) : "v"(h), "v"(w))
#define ASM_FMACD(d, h, w, ROT)                                              \
    asm volatile("v_fmac_f32_dpp %0, %1, %2 row_ror:" #ROT                   \
                 " row_mask:0xf bank_mask:0xf"                               \
                 : "+v"(d) : "v"(h), "v"(w))

#define KEEPALIVE16(a)                                                       \
    asm volatile("" : "+v"(a##0), "+v"(a##1), "+v"(a##2), "+v"(a##3),        \
                      "+v"(a##4), "+v"(a##5), "+v"(a##6), "+v"(a##7),        \
                      "+v"(a##8), "+v"(a##9), "+v"(a##10), "+v"(a##11),      \
                      "+v"(a##12), "+v"(a##13), "+v"(a##14), "+v"(a##15))
#define KEEPALIVE4(a, b, c, d)                                               \
    asm volatile("" : "+v"(a), "+v"(b), "+v"(c), "+v"(d))

// ---- one GRU step, priority-scheduled ----
// MODE 0 = real; 1 = trans->fma stub (same dep shape); 2 = dot->stub.
// Dot split into two latency-matched half-chains per gate; r/n gates issued
// first (critical path: ar -> Er -> r -> u -> En -> rn -> hj), z-gate last
// (only needed at the final blend). Blend: hj' = z*h + (1-z)*(1-2*rn)
//   = s1 + rn*m2o with q=z*h, oz=Ez*z(=1-z), s1=q+oz, m2o=-2*oz (all off-path).
template <int MODE>
__device__ __forceinline__ float gru_step(float hj, v4f P,
    const float (&wr)[8], const float (&wz)[8], const float (&wn)[8], float bhn)
{
    float ra, rb, na, nb, za, zb;
    if constexpr (MODE != 2) {
        ASM_FMA (ra, wr[0], hj, P.x);       // plain ops fill the 2-wait-state
        ASM_FMA (na, wn[0], hj, bhn);       // window before DPP reads hj
        ASM_MULD(rb, hj, wr[4], 8);
        ASM_MULD(nb, hj, wn[4], 8);
        ASM_FMACD(ra, hj, wr[1], 2);   ASM_FMACD(na, hj, wn[1], 2);
        ASM_FMACD(rb, hj, wr[5], 10);  ASM_FMACD(nb, hj, wn[5], 10);
        ASM_FMACD(ra, hj, wr[2], 4);   ASM_FMACD(na, hj, wn[2], 4);
        ASM_FMACD(rb, hj, wr[6], 12);  ASM_FMACD(nb, hj, wn[6], 12);
        ASM_FMACD(ra, hj, wr[3], 6);   ASM_FMACD(na, hj, wn[3], 6);
        ASM_FMACD(rb, hj, wr[7], 14);  ASM_FMACD(nb, hj, wn[7], 14);
    } else {
        ra = fmaf(wr[0], hj, P.x);  rb = wr[4] * hj;
        na = fmaf(wn[0], hj, bhn);  nb = wn[4] * hj;
    }
    const float ar = ra + rb;
    float Er;
    if constexpr (MODE == 1) Er = fmaf(ar, 1e-4f, 1.0f);
    else                     Er = ex2(ar);
    if constexpr (MODE != 2) {
        ASM_FMA (za, wz[0], hj, P.y);
        ASM_MULD(zb, hj, wz[4], 8);
        ASM_FMACD(za, hj, wz[1], 2);
        ASM_FMACD(zb, hj, wz[5], 10);
        ASM_FMACD(za, hj, wz[2], 4);
        ASM_FMACD(zb, hj, wz[6], 12);
        ASM_FMACD(za, hj, wz[3], 6);
        ASM_FMACD(zb, hj, wz[7], 14);
    } else {
        za = fmaf(wz[0], hj, P.y);  zb = wz[4] * hj;
    }
    const float an_ = na + nb;
    float r;
    if constexpr (MODE == 1) r = fmaf(Er, 0.125f, 0.25f);
    else                     r = rcp(1.0f + Er);
    const float az = za + zb;
    float Ez;
    if constexpr (MODE == 1) Ez = fmaf(az, 1e-4f, 1.0f);
    else                     Ez = ex2(az);
    const float u = fmaf(r, an_, P.z);
    float En;
    if constexpr (MODE == 1) En = fmaf(u, 1e-4f, 1.0f);
    else                     En = ex2(u);
    float z;
    if constexpr (MODE == 1) z = fmaf(Ez, 0.125f, 0.25f);
    else                     z = rcp(1.0f + Ez);
    const float q   = z * hj;
    const float oz  = Ez * z;            // exact 1-z
    const float s1  = q + oz;
    const float m2o = -2.0f * oz;
    float rn;
    if constexpr (MODE == 1) rn = fmaf(En, 0.125f, 0.25f);
    else                     rn = rcp(1.0f + En);
    return fmaf(rn, m2o, s1);            // z*h + (1-z)*(1 - 2/(1+En))
}

// ---- producer: prescaled input projections for one 16-step chunk ----
template <int IN, int STRIDE>
__device__ __forceinline__ void produce_chunk(
    const float* __restrict__ xb, int t0,
    const float (&ur)[4], const float (&uz)[4], const float (&un)[4],
    float cr, float cz, float cn,
    float4* __restrict__ dst, int lane)
{
    const float* bp = xb + (size_t)t0 * STRIDE;
#define PLOAD4(i) v4f x##i = *reinterpret_cast<const v4f*>(bp + (i) * STRIDE);
#define PLOAD2(i) v2f x##i = *reinterpret_cast<const v2f*>(bp + (i) * STRIDE);
#define PSTORE(i)                                                            \
    {                                                                        \
        float a = cr, b = cz, c = cn;                                        \
        _Pragma("unroll")                                                    \
        for (int i2 = 0; i2 < IN; ++i2) {                                    \
            a = fmaf(ur[i2], x##i[i2], a);                                   \
            b = fmaf(uz[i2], x##i[i2], b);                                   \
            c = fmaf(un[i2], x##i[i2], c);                                   \
        }                                                                    \
        dst[(i) * 64 + lane] = make_float4(a, b, c, 0.0f);                   \
    }
    if constexpr (IN == 4) {
        PLOAD4(0) PLOAD4(1) PLOAD4(2) PLOAD4(3) PLOAD4(4) PLOAD4(5)
        PLOAD4(6) PLOAD4(7) PLOAD4(8) PLOAD4(9) PLOAD4(10) PLOAD4(11)
        PLOAD4(12) PLOAD4(13) PLOAD4(14) PLOAD4(15)
        KEEPALIVE16(x);
        PSTORE(0) PSTORE(1) PSTORE(2) PSTORE(3) PSTORE(4) PSTORE(5)
        PSTORE(6) PSTORE(7) PSTORE(8) PSTORE(9) PSTORE(10) PSTORE(11)
        PSTORE(12) PSTORE(13) PSTORE(14) PSTORE(15)
    } else {
        PLOAD2(0) PLOAD2(1) PLOAD2(2) PLOAD2(3) PLOAD2(4) PLOAD2(5)
        PLOAD2(6) PLOAD2(7) PLOAD2(8) PLOAD2(9) PLOAD2(10) PLOAD2(11)
        PLOAD2(12) PLOAD2(13) PLOAD2(14) PLOAD2(15)
        KEEPALIVE16(x);
        PSTORE(0) PSTORE(1) PSTORE(2) PSTORE(3) PSTORE(4) PSTORE(5)
        PSTORE(6) PSTORE(7) PSTORE(8) PSTORE(9) PSTORE(10) PSTORE(11)
        PSTORE(12) PSTORE(13) PSTORE(14) PSTORE(15)
    }
#undef PLOAD4
#undef PLOAD2
#undef PSTORE
}

// ---- consumer: 16 steps; staggered pinned preload (counted lgkmcnt) ----
__device__ __forceinline__ float consume_chunk(
    float hj, const float4* __restrict__ src, int lane,
    const float (&wr)[8], const float (&wz)[8], const float (&wn)[8], float bhn)
{
    const v4f* sp = reinterpret_cast<const v4f*>(src);
#define CLOAD(i) v4f p##i = sp[(i) * 64 + lane];
    CLOAD(0) CLOAD(1) CLOAD(2) CLOAD(3) CLOAD(4) CLOAD(5) CLOAD(6) CLOAD(7)
    CLOAD(8) CLOAD(9) CLOAD(10) CLOAD(11) CLOAD(12) CLOAD(13) CLOAD(14) CLOAD(15)
#undef CLOAD
    asm volatile("" ::: "memory");   // pin all 16 ds_read issues above this point
    KEEPALIVE4(p0, p1, p2, p3);      // lgkmcnt(12): wait only for first 4
    hj = gru_step<0>(hj, p0, wr, wz, wn, bhn);
    hj = gru_step<0>(hj, p1, wr, wz, wn, bhn);
    hj = gru_step<0>(hj, p2, wr, wz, wn, bhn);
    hj = gru_step<0>(hj, p3, wr, wz, wn, bhn);
    KEEPALIVE4(p4, p5, p6, p7);      // effectively free by now
    hj = gru_step<0>(hj, p4, wr, wz, wn, bhn);
    hj = gru_step<0>(hj, p5, wr, wz, wn, bhn);
    hj = gru_step<0>(hj, p6, wr, wz, wn, bhn);
    hj = gru_step<0>(hj, p7, wr, wz, wn, bhn);
    KEEPALIVE4(p8, p9, p10, p11);
    hj = gru_step<0>(hj, p8, wr, wz, wn, bhn);
    hj = gru_step<0>(hj, p9, wr, wz, wn, bhn);
    hj = gru_step<0>(hj, p10, wr, wz, wn, bhn);
    hj = gru_step<0>(hj, p11, wr, wz, wn, bhn);
    KEEPALIVE4(p12, p13, p14, p15);
    hj = gru_step<0>(hj, p12, wr, wz, wn, bhn);
    hj = gru_step<0>(hj, p13, wr, wz, wn, bhn);
    hj = gru_step<0>(hj, p14, wr, wz, wn, bhn);
    hj = gru_step<0>(hj, p15, wr, wz, wn, bhn);
    return hj;
}

// block = 256 threads = 4 waves: consumers (bbox/flow) + producers (bbox/flow)
__global__ __launch_bounds__(256, 1)
void gru_fused_kernel(const float* __restrict__ bbox, const float* __restrict__ flow,
                      const float* __restrict__ Wih_b, const float* __restrict__ Whh_b,
                      const float* __restrict__ bih_b, const float* __restrict__ bhh_b,
                      const float* __restrict__ Wih_f, const float* __restrict__ Whh_f,
                      const float* __restrict__ bih_f, const float* __restrict__ bhh_f,
                      float* __restrict__ out, int T)
{
    const float NL2E = -1.4426950408889634f;  // -log2(e)
    const float L2E2 =  2.8853900817779268f;  //  2*log2(e)

    __shared__ float4 projLDS[2][2][CHUNK * 64];    // 64 KiB, lane-linear slots
    __shared__ float sh[2][8][HDIM];

    const int tid  = threadIdx.x;
    const int wave = tid >> 6;
    const int lane = tid & 63;
    const int gru  = wave & 1;            // 0 = bbox, 1 = flow
    const bool is_cons = (wave < 2);
    const int NC = T / CHUNK;             // 32

    const int eloc = ((lane >> 4) << 1) | (lane & 1);   // element 0..7
    const int j    = (lane & 15) >> 1;                  // hidden unit 0..7

    float wr[8], wz[8], wn[8];
    float bhn = 0.0f;
    float ur[4] = {0, 0, 0, 0}, uz[4] = {0, 0, 0, 0}, un[4] = {0, 0, 0, 0};
    float cr = 0.0f, cz = 0.0f, cn = 0.0f;
    const float* pxb = nullptr;

    if (is_cons) {
        const float* Whh = gru ? Whh_f : Whh_b;
        const float* bhh = gru ? bhh_f : bhh_b;
        float nbp = DPP_ROR((float)j, 2);
        const int dstep = (nbp == (float)((j + 1) & 7)) ? 1 : 7;
#pragma unroll
        for (int m = 0; m < 8; ++m) {
            const int k = (j + dstep * m) & 7;
            wr[m] = NL2E * Whh[(j     ) * HDIM + k];
            wz[m] = NL2E * Whh[(j +  8) * HDIM + k];
            wn[m] = L2E2 * Whh[(j + 16) * HDIM + k];
        }
        bhn = L2E2 * bhh[j + 16];
    } else {
        const float* Wih = gru ? Wih_f : Wih_b;
        const float* bih = gru ? bih_f : bih_b;
        const float* bhh = gru ? bhh_f : bhh_b;
        const int IN = gru ? 2 : 4;
        const int pe = blockIdx.x * 8 + eloc;
        pxb = gru ? (flow + (size_t)pe * T * 50 + 24)
                  : (bbox + (size_t)pe * T * 4);
        for (int i = 0; i < IN; ++i) {
            ur[i] = NL2E * Wih[(j     ) * IN + i];
            uz[i] = NL2E * Wih[(j +  8) * IN + i];
            un[i] = L2E2 * Wih[(j + 16) * IN + i];
        }
        cr = NL2E * (bih[j]     + bhh[j]);
        cz = NL2E * (bih[j + 8] + bhh[j + 8]);
        cn = L2E2 * bih[j + 16];
    }

    float hj = 0.0f;

    if (!is_cons) {
        float4* dst = projLDS[0][gru];
        if (gru == 0) produce_chunk<4, 4 >(pxb, 0, ur, uz, un, cr, cz, cn, dst, lane);
        else          produce_chunk<2, 50>(pxb, 0, ur, uz, un, cr, cz, cn, dst, lane);
    }
    __syncthreads();

    for (int c = 0; c < NC; ++c) {
        if (is_cons) {
            hj = consume_chunk(hj, projLDS[c & 1][gru], lane, wr, wz, wn, bhn);
        } else if (c + 1 < NC) {
            float4* dst = projLDS[(c + 1) & 1][gru];
            if (gru == 0) produce_chunk<4, 4 >(pxb, (c + 1) * CHUNK, ur, uz, un, cr, cz, cn, dst, lane);
            else          produce_chunk<2, 50>(pxb, (c + 1) * CHUNK, ur, uz, un, cr, cz, cn, dst, lane);
        }
        __syncthreads();
    }

    if (is_cons) sh[gru][eloc][j] = hj;
    __syncthreads();
    if (wave == 0) {
        const int e = blockIdx.x * 8 + eloc;
        out[(size_t)e * HDIM + j] = 0.5f * (sh[0][eloc][j] + sh[1][eloc][j]);
    }
}

// ---- DIAGNOSTICS: step chain in isolation, 128 steps, stub variants ----
// MODE 0 = full chain (new structure); 1 = trans->fma; 2 = dot->stub.
template <int MODE>
__global__ __launch_bounds__(64, 1)
void abl_step_kernel(const float* __restrict__ Whh, const float* __restrict__ bhh,
                     const float* __restrict__ seed, float* __restrict__ ws,
                     size_t ws_bytes, int nsteps)
{
    const float NL2E = -1.4426950408889634f;
    const float L2E2 =  2.8853900817779268f;
    const int lane = threadIdx.x & 63;
    const int j    = (lane & 15) >> 1;

    float nbp = DPP_ROR((float)j, 2);
    const int dstep = (nbp == (float)((j + 1) & 7)) ? 1 : 7;
    float wr[8], wz[8], wn[8];
#pragma unroll
    for (int m = 0; m < 8; ++m) {
        const int k = (j + dstep * m) & 7;
        wr[m] = NL2E * Whh[(j     ) * HDIM + k];
        wz[m] = NL2E * Whh[(j +  8) * HDIM + k];
        wn[m] = L2E2 * Whh[(j + 16) * HDIM + k];
    }
    const float bhn = L2E2 * bhh[j + 16];

    const v4f* sp = reinterpret_cast<const v4f*>(seed) + (size_t)blockIdx.x * 64;
#define ALOAD(i) v4f p##i = sp[(i) * 4 + (lane & 3)];
    ALOAD(0) ALOAD(1) ALOAD(2) ALOAD(3) ALOAD(4) ALOAD(5) ALOAD(6) ALOAD(7)
    ALOAD(8) ALOAD(9) ALOAD(10) ALOAD(11) ALOAD(12) ALOAD(13) ALOAD(14) ALOAD(15)
    KEEPALIVE16(p);
#undef ALOAD

    float hj = 0.0f;
    const int nc = nsteps / CHUNK;
    for (int c = 0; c < nc; ++c) {
        hj = gru_step<MODE>(hj, p0, wr, wz, wn, bhn);
        hj = gru_step<MODE>(hj, p1, wr, wz, wn, bhn);
        hj = gru_step<MODE>(hj, p2, wr, wz, wn, bhn);
        hj = gru_step<MODE>(hj, p3, wr, wz, wn, bhn);
        hj = gru_step<MODE>(hj, p4, wr, wz, wn, bhn);
        hj = gru_step<MODE>(hj, p5, wr, wz, wn, bhn);
        hj = gru_step<MODE>(hj, p6, wr, wz, wn, bhn);
        hj = gru_step<MODE>(hj, p7, wr, wz, wn, bhn);
        hj = gru_step<MODE>(hj, p8, wr, wz, wn, bhn);
        hj = gru_step<MODE>(hj, p9, wr, wz, wn, bhn);
        hj = gru_step<MODE>(hj, p10, wr, wz, wn, bhn);
        hj = gru_step<MODE>(hj, p11, wr, wz, wn, bhn);
        hj = gru_step<MODE>(hj, p12, wr, wz, wn, bhn);
        hj = gru_step<MODE>(hj, p13, wr, wz, wn, bhn);
        hj = gru_step<MODE>(hj, p14, wr, wz, wn, bhn);
        hj = gru_step<MODE>(hj, p15, wr, wz, wn, bhn);
    }

    const size_t idx = (size_t)(MODE * 8 + blockIdx.x) * 64 + lane;
    if ((idx + 1) * sizeof(float) <= ws_bytes) ws[idx] = hj;
}

extern "C" void kernel_launch(void* const* d_in, const int* in_sizes, int n_in,
                              void* d_out, int out_size, void* d_ws, size_t ws_size,
                              hipStream_t stream) {
    const float* bbox  = (const float*)d_in[0];
    const float* flow  = (const float*)d_in[1];
    const float* Wih_b = (const float*)d_in[2];
    const float* Whh_b = (const float*)d_in[3];
    const float* bih_b = (const float*)d_in[4];
    const float* bhh_b = (const float*)d_in[5];
    const float* Wih_f = (const float*)d_in[6];
    const float* Whh_f = (const float*)d_in[7];
    const float* bih_f = (const float*)d_in[8];
    const float* bhh_f = (const float*)d_in[9];
    float* out = (float*)d_out;

    const int B = out_size / HDIM;            // 1024
    const int T = in_sizes[0] / (4 * B);      // 512

    gru_fused_kernel<<<dim3(B / 8), dim3(256), 0, stream>>>(
        bbox, flow, Wih_b, Whh_b, bih_b, bhh_b,
        Wih_f, Whh_f, bih_f, bhh_f, out, T);

    // diagnostics (write only to d_ws; 128 steps each, ~16 us total)
    abl_step_kernel<0><<<dim3(8), dim3(64), 0, stream>>>(
        Whh_b, bhh_b, bbox, (float*)d_ws, ws_size, 128);
    abl_step_kernel<1><<<dim3(8), dim3(64), 0, stream>>>(
        Whh_b, bhh_b, bbox, (float*)d_ws, ws_size, 128);
    abl_step_kernel<2><<<dim3(8), dim3(64), 0, stream>>>(
        Whh_b, bhh_b, bbox, (float*)d_ws, ws_size, 128);
}

// Round 12
// 74.537 us; speedup vs baseline: 1.8863x; 1.2555x over previous
//
#include <hip/hip_runtime.h>
#include <type_traits>

#define HDIM 8

typedef float v4f __attribute__((ext_vector_type(4)));
typedef float v2f __attribute__((ext_vector_type(2)));

// ---- fast device math (v_exp_f32 / v_rcp_f32) ----
__device__ __forceinline__ float ex2(float x) {
#if __has_builtin(__builtin_amdgcn_exp2f)
    return __builtin_amdgcn_exp2f(x);
#else
    return exp2f(x);
#endif
}
__device__ __forceinline__ float rcp(float x) {
#if __has_builtin(__builtin_amdgcn_rcpf)
    return __builtin_amdgcn_rcpf(x);
#else
    return 1.0f / x;
#endif
}

// v_mov_b32_dpp row_ror:N (probe only; hot path uses fused fmac_dpp)
#define DPP_ROR(v, N)                                                        \
    __int_as_float(__builtin_amdgcn_update_dpp(                              \
        0, __float_as_int(v), 0x120 + (N), 0xF, 0xF, true))

// ---- single-instruction asm helpers ----
#define ASM_FMA(d, a, b, c)                                                  \
    asm volatile("v_fma_f32 %0, %1, %2, %3"                                  \
                 : "=v"(d) : "v"(a), "v"(b), "v"(c))
#define ASM_MULD(d, h, w, ROT)                                               \
    asm volatile("v_mul_f32_dpp %0, %1, %2 row_ror:" #ROT                    \
                 " row_mask:0xf bank_mask:0xf"                               \
                 : "=v"(d) : "v"(h), "v"(w))
#define ASM_FMACD(d, h, w, ROT)                                              \
    asm volatile("v_fmac_f32_dpp %0, %1, %2 row_ror:" #ROT                   \
                 " row_mask:0xf bank_mask:0xf"                               \
                 : "+v"(d) : "v"(h), "v"(w))

// issue-order pin: memory ops above cannot sink below, and vice versa
#define MEMBAR asm volatile("" ::: "memory")

// ---- one GRU step (round-11 math, verified absmax 9.5e-7) ----
// Dot split into two latency-matched half-chains per gate; r/n gates first,
// z-gate last (needed only at the blend). Blend: hj' = z*h + (1-z)*(1-2*rn)
//   = s1 + rn*m2o with q=z*h, oz=Ez*z(=1-z), s1=q+oz, m2o=-2*oz.
__device__ __forceinline__ float gru_step(float hj, v4f P,
    const float (&wr)[8], const float (&wz)[8], const float (&wn)[8], float bhn)
{
    float ra, rb, na, nb, za, zb;
    ASM_FMA (ra, wr[0], hj, P.x);       // plain ops fill the 2-wait-state
    ASM_FMA (na, wn[0], hj, bhn);       // window before DPP reads hj
    ASM_MULD(rb, hj, wr[4], 8);
    ASM_MULD(nb, hj, wn[4], 8);
    ASM_FMACD(ra, hj, wr[1], 2);   ASM_FMACD(na, hj, wn[1], 2);
    ASM_FMACD(rb, hj, wr[5], 10);  ASM_FMACD(nb, hj, wn[5], 10);
    ASM_FMACD(ra, hj, wr[2], 4);   ASM_FMACD(na, hj, wn[2], 4);
    ASM_FMACD(rb, hj, wr[6], 12);  ASM_FMACD(nb, hj, wn[6], 12);
    ASM_FMACD(ra, hj, wr[3], 6);   ASM_FMACD(na, hj, wn[3], 6);
    ASM_FMACD(rb, hj, wr[7], 14);  ASM_FMACD(nb, hj, wn[7], 14);
    const float ar = ra + rb;
    const float Er = ex2(ar);
    ASM_FMA (za, wz[0], hj, P.y);
    ASM_MULD(zb, hj, wz[4], 8);
    ASM_FMACD(za, hj, wz[1], 2);
    ASM_FMACD(zb, hj, wz[5], 10);
    ASM_FMACD(za, hj, wz[2], 4);
    ASM_FMACD(zb, hj, wz[6], 12);
    ASM_FMACD(za, hj, wz[3], 6);
    ASM_FMACD(zb, hj, wz[7], 14);
    const float an_ = na + nb;
    const float r  = rcp(1.0f + Er);
    const float az = za + zb;
    const float Ez = ex2(az);
    const float u  = fmaf(r, an_, P.z);
    const float En = ex2(u);
    const float z  = rcp(1.0f + Ez);
    const float q   = z * hj;
    const float oz  = Ez * z;            // exact 1-z
    const float s1  = q + oz;
    const float m2o = -2.0f * oz;
    const float rn  = rcp(1.0f + En);
    return fmaf(rn, m2o, s1);            // z*h + (1-z)*(1 - 2/(1+En))
}

// ---- self-contained consumer: direct global loads, keepalive-pinned,
// 8-step double-buffered register prefetch, inline projections.
// No LDS, no barriers, no producer waves.
template <int IN, int STRIDE>
__device__ __forceinline__ float gru_run(
    const float* __restrict__ px, int T,
    const float (&ur)[4], const float (&uz)[4], const float (&un)[4],
    float cr, float cz, float cn,
    const float (&wr)[8], const float (&wz)[8], const float (&wn)[8], float bhn)
{
    using vx = std::conditional_t<IN == 4, v4f, v2f>;
    auto LD = [&](int t) -> vx {
        return *reinterpret_cast<const vx*>(px + (size_t)t * STRIDE);
    };
    auto PROJ = [&](vx x) -> v4f {
        float a = cr, b = cz, c = cn;
#pragma unroll
        for (int i = 0; i < IN; ++i) {
            a = fmaf(ur[i], x[i], a);
            b = fmaf(uz[i], x[i], b);
            c = fmaf(un[i], x[i], c);
        }
        return v4f{a, b, c, 0.0f};
    };

    vx A0, A1, A2, A3, A4, A5, A6, A7;
    vx B0, B1, B2, B3, B4, B5, B6, B7;

    A0 = LD(0); A1 = LD(1); A2 = LD(2); A3 = LD(3);
    A4 = LD(4); A5 = LD(5); A6 = LD(6); A7 = LD(7);
    MEMBAR;                               // pin A-load issue before the loop

    float hj = 0.0f;
    for (int t0 = 0; t0 < T; t0 += 16) {
        // issue next half-chunk's loads; consumed 8 steps (~1600 cy) later
        if (t0 + 8 < T) {
            B0 = LD(t0 + 8);  B1 = LD(t0 + 9);  B2 = LD(t0 + 10); B3 = LD(t0 + 11);
            B4 = LD(t0 + 12); B5 = LD(t0 + 13); B6 = LD(t0 + 14); B7 = LD(t0 + 15);
        }
        MEMBAR;
        hj = gru_step(hj, PROJ(A0), wr, wz, wn, bhn);
        hj = gru_step(hj, PROJ(A1), wr, wz, wn, bhn);
        hj = gru_step(hj, PROJ(A2), wr, wz, wn, bhn);
        hj = gru_step(hj, PROJ(A3), wr, wz, wn, bhn);
        hj = gru_step(hj, PROJ(A4), wr, wz, wn, bhn);
        hj = gru_step(hj, PROJ(A5), wr, wz, wn, bhn);
        hj = gru_step(hj, PROJ(A6), wr, wz, wn, bhn);
        hj = gru_step(hj, PROJ(A7), wr, wz, wn, bhn);
        if (t0 + 16 < T) {
            A0 = LD(t0 + 16); A1 = LD(t0 + 17); A2 = LD(t0 + 18); A3 = LD(t0 + 19);
            A4 = LD(t0 + 20); A5 = LD(t0 + 21); A6 = LD(t0 + 22); A7 = LD(t0 + 23);
        }
        MEMBAR;
        hj = gru_step(hj, PROJ(B0), wr, wz, wn, bhn);
        hj = gru_step(hj, PROJ(B1), wr, wz, wn, bhn);
        hj = gru_step(hj, PROJ(B2), wr, wz, wn, bhn);
        hj = gru_step(hj, PROJ(B3), wr, wz, wn, bhn);
        hj = gru_step(hj, PROJ(B4), wr, wz, wn, bhn);
        hj = gru_step(hj, PROJ(B5), wr, wz, wn, bhn);
        hj = gru_step(hj, PROJ(B6), wr, wz, wn, bhn);
        hj = gru_step(hj, PROJ(B7), wr, wz, wn, bhn);
    }
    return hj;
}

// block = 128 threads = 2 waves: wave 0 = bbox GRU, wave 1 = flow GRU,
// same 8 batch elements. Single __syncthreads at the end for the combine.
// Lane mapping: row = lane>>4 (16-lane DPP row), p = lane&15;
// element el = (row<<1)|(p&1), hidden unit j = p>>1.
__global__ __launch_bounds__(128, 1)
void gru_fused_kernel(const float* __restrict__ bbox, const float* __restrict__ flow,
                      const float* __restrict__ Wih_b, const float* __restrict__ Whh_b,
                      const float* __restrict__ bih_b, const float* __restrict__ bhh_b,
                      const float* __restrict__ Wih_f, const float* __restrict__ Whh_f,
                      const float* __restrict__ bih_f, const float* __restrict__ bhh_f,
                      float* __restrict__ out, int T)
{
    const float NL2E = -1.4426950408889634f;  // -log2(e)
    const float L2E2 =  2.8853900817779268f;  //  2*log2(e)

    __shared__ float sh[2][8][HDIM];          // end-combine only (512 B)

    const int tid  = threadIdx.x;
    const int wave = tid >> 6;                // 0 = bbox, 1 = flow
    const int lane = tid & 63;
    const int eloc = ((lane >> 4) << 1) | (lane & 1);   // element 0..7
    const int j    = (lane & 15) >> 1;                  // hidden unit 0..7
    const int e    = blockIdx.x * 8 + eloc;

    const float* Wih = wave ? Wih_f : Wih_b;
    const float* Whh = wave ? Whh_f : Whh_b;
    const float* bih = wave ? bih_f : bih_b;
    const float* bhh = wave ? bhh_f : bhh_b;
    const int IN = wave ? 2 : 4;

    // probe row_ror direction: partner of rotation 2 holds unit (j +- 1)&7
    float nbp = DPP_ROR((float)j, 2);
    const int dstep = (nbp == (float)((j + 1) & 7)) ? 1 : 7;

    // recurrent weights in rotation order, prescaled by -log2e / 2log2e
    float wr[8], wz[8], wn[8];
#pragma unroll
    for (int m = 0; m < 8; ++m) {
        const int k = (j + dstep * m) & 7;
        wr[m] = NL2E * Whh[(j     ) * HDIM + k];
        wz[m] = NL2E * Whh[(j +  8) * HDIM + k];
        wn[m] = L2E2 * Whh[(j + 16) * HDIM + k];
    }
    const float bhn = L2E2 * bhh[j + 16];

    // input weights + fused biases (prescaled)
    float ur[4] = {0, 0, 0, 0}, uz[4] = {0, 0, 0, 0}, un[4] = {0, 0, 0, 0};
    for (int i = 0; i < IN; ++i) {
        ur[i] = NL2E * Wih[(j     ) * IN + i];
        uz[i] = NL2E * Wih[(j +  8) * IN + i];
        un[i] = L2E2 * Wih[(j + 16) * IN + i];
    }
    const float cr = NL2E * (bih[j]     + bhh[j]);
    const float cz = NL2E * (bih[j + 8] + bhh[j + 8]);
    const float cn = L2E2 * bih[j + 16];

    float hT;
    if (wave == 0) {
        const float* px = bbox + (size_t)e * T * 4;
        hT = gru_run<4, 4>(px, T, ur, uz, un, cr, cz, cn, wr, wz, wn, bhn);
    } else {
        // flow[e, t, 2, 2, :] -> offset (e*T + t)*50 + 24, stride 50 floats
        const float* px = flow + (size_t)e * T * 50 + 24;
        hT = gru_run<2, 50>(px, T, ur, uz, un, cr, cz, cn, wr, wz, wn, bhn);
    }

    sh[wave][eloc][j] = hT;
    __syncthreads();
    if (wave == 0) {
        out[(size_t)e * HDIM + j] = 0.5f * (sh[0][eloc][j] + sh[1][eloc][j]);
    }
}

extern "C" void kernel_launch(void* const* d_in, const int* in_sizes, int n_in,
                              void* d_out, int out_size, void* d_ws, size_t ws_size,
                              hipStream_t stream) {
    const float* bbox  = (const float*)d_in[0];
    const float* flow  = (const float*)d_in[1];
    const float* Wih_b = (const float*)d_in[2];
    const float* Whh_b = (const float*)d_in[3];
    const float* bih_b = (const float*)d_in[4];
    const float* bhh_b = (const float*)d_in[5];
    const float* Wih_f = (const float*)d_in[6];
    const float* Whh_f = (const float*)d_in[7];
    const float* bih_f = (const float*)d_in[8];
    const float* bhh_f = (const float*)d_in[9];
    float* out = (float*)d_out;

    const int B = out_size / HDIM;            // 1024
    const int T = in_sizes[0] / (4 * B);      // 512

    dim3 grid(B / 8), block(128);
    gru_fused_kernel<<<grid, block, 0, stream>>>(
        bbox, flow, Wih_b, Whh_b, bih_b, bhh_b,
        Wih_f, Whh_f, bih_f, bhh_f, out, T);
}